// Round 1
// baseline (10986.397 us; speedup 1.0000x reference)
//
#include <hip/hip_runtime.h>
#include <hip/hip_bf16.h>

// LSTM recurrence: T=512, B=64, D=H=1024, gates 4H=4096.
// Strategy (round 1, correctness-first):
//   prep: cast+transpose Wi,Wh -> bf16 [4H][K] in ws; c(f32), h(bf16, dbuf)
//   512 step launches: fused (x@Wi + h@Wh + b) via 16x16x32 bf16 MFMA,
//   gate exchange via LDS, f32 cell state, f32 output.
// ws usage: WiT 8MB + WhT 8MB + c 256KB + h dbuf 256KB ~= 16.9 MB.

#define T_STEPS 512
#define BATCH   64
#define DIM     1024   // D == H
#define NG      4096   // 4*H

typedef __attribute__((ext_vector_type(8))) short frag8;   // 8 x bf16
typedef __attribute__((ext_vector_type(4))) float f32x4;

__device__ __forceinline__ short f2bf(float f) {
    union { float f; unsigned u; } v; v.f = f;
    unsigned r = v.u + 0x7fffu + ((v.u >> 16) & 1u);   // RNE
    return (short)(r >> 16);
}

__device__ __forceinline__ float sigm(float x) { return 1.0f / (1.0f + __expf(-x)); }
__device__ __forceinline__ float tanh_fast(float x) { return 1.0f - 2.0f / (__expf(2.0f * x) + 1.0f); }

// W: [DIM][NG] f32 row-major  ->  WT: [NG][DIM] bf16 row-major
__global__ __launch_bounds__(256)
void cast_transpose(const float* __restrict__ W, short* __restrict__ WT) {
    __shared__ float tile[32][33];
    int k0 = blockIdx.x * 32;          // over DIM (rows of W)
    int n0 = blockIdx.y * 32;          // over NG  (cols of W)
    int tx = threadIdx.x & 31, ty = threadIdx.x >> 5;   // ty: 0..7
    #pragma unroll
    for (int i = 0; i < 32; i += 8)
        tile[ty + i][tx] = W[(size_t)(k0 + ty + i) * NG + n0 + tx];
    __syncthreads();
    #pragma unroll
    for (int i = 0; i < 32; i += 8)
        WT[(size_t)(n0 + ty + i) * DIM + k0 + tx] = f2bf(tile[tx][ty + i]);
}

__global__ __launch_bounds__(256)
void init_state(const float* __restrict__ c0, const float* __restrict__ h0,
                float* __restrict__ c, short* __restrict__ hbuf) {
    int i = blockIdx.x * 256 + threadIdx.x;   // 256 blocks * 256 = 65536 = B*H
    c[i] = c0[i];
    hbuf[i] = f2bf(h0[i]);
}

// One timestep. grid = (64 j-tiles, 4 batch-tiles), 256 threads (4 waves).
// wave w computes gate w's 16x16 tile: cols n = w*1024 + jt*16 + (lane&15).
__global__ __launch_bounds__(256)
void lstm_step(const float* __restrict__ x_t,    // [B][D] f32 (x + t*B*D)
               const short* __restrict__ WiT,    // [NG][DIM] bf16
               const short* __restrict__ WhT,    // [NG][DIM] bf16
               const float* __restrict__ bias,   // [NG]
               float* __restrict__ c,            // [B][H] f32 (in/out)
               const short* __restrict__ hsrc,   // [B][H] bf16 (prev h)
               short* __restrict__ hdst,         // [B][H] bf16 (new h)
               float* __restrict__ y_t)          // [B][H] f32 (out + t*B*H)
{
    const int jt   = blockIdx.x;            // 0..63 hidden j-tile
    const int bt   = blockIdx.y;            // 0..3 batch tile
    const int lane = threadIdx.x & 63;
    const int wave = threadIdx.x >> 6;      // gate: 0=i 1=f 2=g 3=o
    const int m    = lane & 15;
    const int q    = lane >> 4;

    const float* xrow = x_t  + (size_t)(bt * 16 + m) * DIM;
    const short* hrow = hsrc + (size_t)(bt * 16 + m) * DIM;
    const int ncol    = wave * DIM + jt * 16 + m;       // global gate column
    const short* wi   = WiT + (size_t)ncol * DIM;
    const short* wh   = WhT + (size_t)ncol * DIM;

    const float bv = bias[ncol];
    f32x4 acc = { bv, bv, bv, bv };    // bias folded in (C col = lane&15 = ncol's col)

    // x @ Wi over K = DIM (cast x f32->bf16 in-register)
    #pragma unroll 4
    for (int kc = 0; kc < DIM; kc += 32) {
        const int ko = kc + q * 8;
        float4 x0 = *(const float4*)(xrow + ko);
        float4 x1 = *(const float4*)(xrow + ko + 4);
        frag8 a;
        a[0] = f2bf(x0.x); a[1] = f2bf(x0.y); a[2] = f2bf(x0.z); a[3] = f2bf(x0.w);
        a[4] = f2bf(x1.x); a[5] = f2bf(x1.y); a[6] = f2bf(x1.z); a[7] = f2bf(x1.w);
        frag8 bfr = *(const frag8*)(wi + ko);
        acc = __builtin_amdgcn_mfma_f32_16x16x32_bf16(a, bfr, acc, 0, 0, 0);
    }
    // h @ Wh over K = DIM (h already bf16)
    #pragma unroll 4
    for (int kc = 0; kc < DIM; kc += 32) {
        const int ko = kc + q * 8;
        frag8 a   = *(const frag8*)(hrow + ko);
        frag8 bfr = *(const frag8*)(wh + ko);
        acc = __builtin_amdgcn_mfma_f32_16x16x32_bf16(a, bfr, acc, 0, 0, 0);
    }

    // D layout: row=(lane>>4)*4+r (batch-in-tile), col=lane&15 (j-in-tile)
    __shared__ float gsm[4][16][17];
    #pragma unroll
    for (int r = 0; r < 4; ++r)
        gsm[wave][q * 4 + r][m] = acc[r];
    __syncthreads();

    // elementwise: thread -> (batch-in-tile, j-in-tile)
    const int bl = threadIdx.x >> 4;    // 0..15
    const int j  = threadIdx.x & 15;
    const float ig = sigm(gsm[0][bl][j]);
    const float fg = sigm(gsm[1][bl][j]);
    const float gg = tanh_fast(gsm[2][bl][j]);
    const float og = sigm(gsm[3][bl][j]);

    const int gj  = jt * 16 + j;
    const int idx = (bt * 16 + bl) * DIM + gj;
    const float cn = fg * c[idx] + ig * gg;
    c[idx] = cn;
    const float hn = og * tanh_fast(cn);
    y_t[idx]  = hn;
    hdst[idx] = f2bf(hn);
}

extern "C" void kernel_launch(void* const* d_in, const int* in_sizes, int n_in,
                              void* d_out, int out_size, void* d_ws, size_t ws_size,
                              hipStream_t stream) {
    const float* x  = (const float*)d_in[0];   // [T][B][D]
    const float* c0 = (const float*)d_in[1];   // [B][H]
    const float* h0 = (const float*)d_in[2];   // [B][H]
    const float* Wi = (const float*)d_in[3];   // [D][4H]
    const float* Wh = (const float*)d_in[4];   // [H][4H]
    const float* b  = (const float*)d_in[5];   // [4H]
    float* out = (float*)d_out;                // [T][B][H]

    char* ws = (char*)d_ws;
    const size_t WBYTES = (size_t)NG * DIM * 2;          // 8 MB each
    short* WiT  = (short*)ws;
    short* WhT  = (short*)(ws + WBYTES);
    float* c    = (float*)(ws + 2 * WBYTES);             // 256 KB
    short* hb0  = (short*)(ws + 2 * WBYTES + (size_t)BATCH * DIM * 4);
    short* hb1  = hb0 + BATCH * DIM;                     // 128 KB each

    cast_transpose<<<dim3(DIM / 32, NG / 32), 256, 0, stream>>>(Wi, WiT);
    cast_transpose<<<dim3(DIM / 32, NG / 32), 256, 0, stream>>>(Wh, WhT);
    init_state<<<dim3(BATCH * DIM / 256), 256, 0, stream>>>(c0, h0, c, hb0);

    for (int t = 0; t < T_STEPS; ++t) {
        const short* hs = (t & 1) ? hb1 : hb0;
        short*       hd = (t & 1) ? hb0 : hb1;
        lstm_step<<<dim3(64, 4), 256, 0, stream>>>(
            x + (size_t)t * BATCH * DIM, WiT, WhT, b, c, hs, hd,
            out + (size_t)t * BATCH * DIM);
    }
}